// Round 2
// baseline (1553.953 us; speedup 1.0000x reference)
//
#include <hip/hip_runtime.h>

#define D 128
#define EPS 1e-10f

// ---------------------------------------------------------------------------
// K1: row_ptr[b] = first index i with node2graph[i] >= b (node2graph sorted)
// ---------------------------------------------------------------------------
__global__ void rowptr_kernel(const int* __restrict__ n2g, int N_, int B_,
                              int* __restrict__ row_ptr) {
    int b = blockIdx.x * 256 + threadIdx.x;
    if (b > B_) return;
    if (b == B_) { row_ptr[b] = N_; return; }
    int lo = 0, hi = N_;
    while (lo < hi) {
        int mid = (lo + hi) >> 1;
        if (n2g[mid] < b) lo = mid + 1; else hi = mid;
    }
    row_ptr[b] = lo;
}

// ---------------------------------------------------------------------------
// K2: b_sum = b_ih + b_hh; step-1 constants h1, c1 (h=c=q_star=0 at step 1)
// gate order (PyTorch): i, f, g, o at j = [0:128),[128:256),[256:384),[384:512)
// ---------------------------------------------------------------------------
__global__ void init_consts_kernel(const float* __restrict__ b_ih,
                                   const float* __restrict__ b_hh,
                                   float* __restrict__ b_sum,
                                   float* __restrict__ c1,
                                   float* __restrict__ h1) {
    int t = threadIdx.x;  // 512 threads, 1 block
    __shared__ float bs[512];
    float v = b_ih[t] + b_hh[t];
    b_sum[t] = v;
    bs[t] = v;
    __syncthreads();
    if (t < D) {
        float ig = 1.f / (1.f + __expf(-bs[t]));
        float gg = tanhf(bs[256 + t]);
        float c  = ig * gg;                       // f*c0 = 0
        float og = 1.f / (1.f + __expf(-bs[384 + t]));
        c1[t] = c;
        h1[t] = og * tanhf(c);
    }
}

// ---------------------------------------------------------------------------
// K3: W1[j][k] = w_ih[j][k] + w_hh[j][k]  (fold hidden weights into input half)
//     const2[j] = b_sum[j] + sum_k h1[k] * W1[j][k]   (step-2 gate constant)
// ---------------------------------------------------------------------------
__global__ void init_w1_kernel(const float* __restrict__ w_ih,
                               const float* __restrict__ w_hh,
                               const float* __restrict__ b_sum,
                               const float* __restrict__ h1,
                               float* __restrict__ W1,
                               float* __restrict__ const2) {
    int j = blockIdx.x, k = threadIdx.x;
    float w = w_ih[j * 256 + k] + w_hh[j * 128 + k];
    W1[j * 128 + k] = w;
    __shared__ float red[128];
    red[k] = w * h1[k];
    __syncthreads();
    for (int s = 64; s > 0; s >>= 1) {
        if (k < s) red[k] += red[k + s];
        __syncthreads();
    }
    if (k == 0) const2[j] = b_sum[j] + red[0];
}

// ---------------------------------------------------------------------------
// K4: tiled GEMM: gates[b][j] = base[j] + A1[b]·Wa[j] (+ A2[b]·Wb[j])
// ---------------------------------------------------------------------------
#define BM 64
#define BN 64
#define BK 32
__global__ __launch_bounds__(256) void lstm_gemm_kernel(
    const float* __restrict__ A1, const float* __restrict__ Wa, int wa_stride,
    const float* __restrict__ A2, const float* __restrict__ Wb, int wb_stride,
    const float* __restrict__ base, float* __restrict__ gates, int B_) {
    __shared__ float As[BM][BK + 1];
    __shared__ float Bs[BN][BK + 1];
    int b0 = blockIdx.y * BM;
    int j0 = blockIdx.x * BN;
    int tid = threadIdx.x;
    int tx = tid & 15, ty = tid >> 4;
    float acc[4][4] = {};
    int nphase = A2 ? 2 : 1;
    for (int phase = 0; phase < nphase; phase++) {
        const float* A = phase ? A2 : A1;
        const float* W = phase ? Wb : Wa;
        int ws = phase ? wb_stride : wa_stride;
        for (int k0 = 0; k0 < 128; k0 += BK) {
            __syncthreads();
            for (int i = tid; i < BM * BK; i += 256) {
                int r = i >> 5, cc = i & 31;
                int bb = b0 + r;
                As[r][cc] = (bb < B_) ? A[(size_t)bb * D + k0 + cc] : 0.f;
            }
            for (int i = tid; i < BN * BK; i += 256) {
                int r = i >> 5, cc = i & 31;
                Bs[r][cc] = W[(size_t)(j0 + r) * ws + k0 + cc];
            }
            __syncthreads();
#pragma unroll
            for (int kk = 0; kk < BK; kk++) {
                float av[4], bv[4];
#pragma unroll
                for (int i = 0; i < 4; i++) av[i] = As[ty * 4 + i][kk];
#pragma unroll
                for (int j = 0; j < 4; j++) bv[j] = Bs[tx * 4 + j][kk];
#pragma unroll
                for (int i = 0; i < 4; i++)
#pragma unroll
                    for (int j = 0; j < 4; j++) acc[i][j] += av[i] * bv[j];
            }
        }
    }
    for (int i = 0; i < 4; i++) {
        int bb = b0 + ty * 4 + i;
        if (bb >= B_) continue;
        for (int j = 0; j < 4; j++) {
            int jj = j0 + tx * 4 + j;
            gates[(size_t)bb * 512 + jj] = acc[i][j] + base[jj];
        }
    }
}

// ---------------------------------------------------------------------------
// K5: elementwise LSTM state update from gates
// ---------------------------------------------------------------------------
__global__ void lstm_elem_kernel(const float* __restrict__ gates,
                                 const float* __restrict__ c_prev, int c_bcast,
                                 float* __restrict__ c_out,
                                 float* __restrict__ h_out, int B_) {
    int t = blockIdx.x * 256 + threadIdx.x;
    if (t >= B_ * D) return;
    int b = t >> 7, d = t & (D - 1);
    const float* g = gates + (size_t)b * 512;
    float ig = 1.f / (1.f + __expf(-g[d]));
    float fg = 1.f / (1.f + __expf(-g[128 + d]));
    float gg = tanhf(g[256 + d]);
    float og = 1.f / (1.f + __expf(-g[384 + d]));
    float cp = c_bcast ? c_prev[d] : c_prev[t];
    float c = fg * cp + ig * gg;
    c_out[t] = c;
    h_out[t] = og * tanhf(c);
}

// ---------------------------------------------------------------------------
// K6: attention — ONE WAVE PER GRAPH, barrier-free, online softmax.
// 3 waves/block (192 thr). Per wave: 32-node x-tile in wave-private LDS,
// T14 async staging (issue next tile's global->reg loads before computing
// current tile), all reductions via shfl_xor. LDS rotation swizzle
// slot(row,d4) = row*32 + ((d4+row)&31) keeps every LDS access pattern at
// its bandwidth optimum (dot: 8 lanes per 4-bank group, distinct lines).
// ---------------------------------------------------------------------------
#define TILE 32
#define WPB 3   // waves per block

__global__ __launch_bounds__(192) void attn_kernel(
    const float* __restrict__ x, const float* __restrict__ q_src, int q_bcast,
    const int* __restrict__ row_ptr, float* __restrict__ out,
    float* __restrict__ final_out, int B_) {
    __shared__ float q_s[WPB][D];
    __shared__ float xs[WPB][TILE * D];   // 48 KB
    __shared__ float w_s[WPB][TILE];

    int tid = threadIdx.x;
    int wave = tid >> 6;
    int lane = tid & 63;
    int b = blockIdx.x * WPB + wave;
    if (b >= B_) return;   // no barriers anywhere -> safe

    const float* qp = q_bcast ? q_src : q_src + (size_t)b * D;
    q_s[wave][lane] = qp[lane];
    q_s[wave][lane + 64] = qp[lane + 64];

    int s = row_ptr[b], e = row_ptr[b + 1];

    float* xw = xs[wave];
    float4* xw4 = (float4*)xw;
    const float4* q4 = (const float4*)q_s[wave];
    const float4* x4 = (const float4*)x;

    float m = -1e30f, lsum = 0.f, acc0 = 0.f, acc1 = 0.f;
    float4 stg[16];

    // prologue: stage tile 0 into registers
    if (s < e) {
#pragma unroll
        for (int j = 0; j < 16; j++) {
            int idx = lane + 64 * j;              // 0..1023
            int row = s + (idx >> 5);
            row = (row < e) ? row : s;            // clamp to a valid row
            stg[j] = x4[(size_t)row * 32 + (idx & 31)];
        }
    }

    int n = lane >> 1, h = lane & 1;
    int u0 = lane >> 2, c0 = lane & 3;

    for (int t0 = s; t0 < e; t0 += TILE) {
        int nt = min(TILE, e - t0);

        // write staged regs -> LDS (rotation swizzle); compiler inserts vmcnt
#pragma unroll
        for (int j = 0; j < 16; j++) {
            int idx = lane + 64 * j;
            int row = idx >> 5, d4 = idx & 31;
            xw4[row * 32 + ((d4 + row) & 31)] = stg[j];
        }

        // T14: issue next tile's loads now; latency hides under compute below
        int t1 = t0 + TILE;
        if (t1 < e) {
#pragma unroll
            for (int j = 0; j < 16; j++) {
                int idx = lane + 64 * j;
                int row = t1 + (idx >> 5);
                row = (row < e) ? row : t1;
                stg[j] = x4[(size_t)row * 32 + (idx & 31)];
            }
        }

        // dot: 2 lanes per node, 64 dims each (ds_read_b128, swizzled)
        float p = 0.f;
#pragma unroll
        for (int j = 0; j < 16; j++) {
            int d4 = h * 16 + j;
            float4 xv = xw4[n * 32 + ((d4 + n) & 31)];
            float4 qv = q4[d4];
            p += xv.x * qv.x + xv.y * qv.y + xv.z * qv.z + xv.w * qv.w;
        }
        p += __shfl_xor(p, 1);
        float prod = (n < nt) ? p : -1e30f;

        // wave-parallel tile max (pairs duplicate -> reduce masks 2..32)
        float tmax = prod;
#pragma unroll
        for (int mask = 2; mask <= 32; mask <<= 1)
            tmax = fmaxf(tmax, __shfl_xor(tmax, mask));
        float m_new = fmaxf(m, tmax);
        float r = __expf(m - m_new);          // first tile: exp(-inf) = 0
        float w = __expf(prod - m_new);       // inactive nodes -> 0

        float tsum = w;
#pragma unroll
        for (int mask = 2; mask <= 32; mask <<= 1)
            tsum += __shfl_xor(tsum, mask);
        lsum = lsum * r + tsum;

        if (h == 0) w_s[wave][n] = w;

        // accumulate: lane owns dims {lane, lane+64}; 2-way LDS reads (free)
        acc0 *= r; acc1 *= r;
#pragma unroll 4
        for (int t = 0; t < nt; t++) {
            float wt = w_s[wave][t];
            acc0 += wt * xw[(t * 32 + ((u0 + t) & 31)) * 4 + c0];
            acc1 += wt * xw[(t * 32 + ((u0 + 16 + t) & 31)) * 4 + c0];
        }
        m = m_new;
    }

    float inv = 1.f / (lsum + EPS);
    float o0 = acc0 * inv, o1 = acc1 * inv;
    if (out) {
        out[(size_t)b * D + lane] = o0;
        out[(size_t)b * D + lane + 64] = o1;
    }
    if (final_out) {
        float* fo = final_out + (size_t)b * 2 * D;
        fo[lane] = q_s[wave][lane];
        fo[lane + 64] = q_s[wave][lane + 64];
        fo[D + lane] = o0;
        fo[D + lane + 64] = o1;
    }
}

// ---------------------------------------------------------------------------
extern "C" void kernel_launch(void* const* d_in, const int* in_sizes, int n_in,
                              void* d_out, int out_size, void* d_ws,
                              size_t ws_size, hipStream_t stream) {
    const float* x    = (const float*)d_in[0];
    const float* w_ih = (const float*)d_in[1];
    const float* w_hh = (const float*)d_in[2];
    const float* b_ih = (const float*)d_in[3];
    const float* b_hh = (const float*)d_in[4];
    const int*   n2g  = (const int*)d_in[5];

    int N_ = in_sizes[0] / D;     // 1,000,000
    int B_ = out_size / (2 * D);  // 10,000

    // workspace carve (256B aligned)
    char* wsb = (char*)d_ws;
    size_t off = 0;
    auto carve = [&](size_t bytes) {
        void* p = wsb + off;
        off = (off + bytes + 255) & ~(size_t)255;
        return p;
    };
    int*   row_ptr = (int*)carve((size_t)(B_ + 1) * 4);
    float* b_sum   = (float*)carve(512 * 4);
    float* c1      = (float*)carve(D * 4);
    float* h1      = (float*)carve(D * 4);
    float* const2  = (float*)carve(512 * 4);
    float* W1      = (float*)carve((size_t)512 * D * 4);
    float* hbuf    = (float*)carve((size_t)B_ * D * 4);
    float* cbuf    = (float*)carve((size_t)B_ * D * 4);
    float* outbuf  = (float*)carve((size_t)B_ * D * 4);
    float* gates   = (float*)carve((size_t)B_ * 512 * 4);
    (void)ws_size;

    const float* W2 = w_ih + D;  // rows of w_ih, column offset 128, stride 256

    // setup
    rowptr_kernel<<<(B_ + 1 + 255) / 256, 256, 0, stream>>>(n2g, N_, B_, row_ptr);
    init_consts_kernel<<<1, 512, 0, stream>>>(b_ih, b_hh, b_sum, c1, h1);
    init_w1_kernel<<<512, 128, 0, stream>>>(w_ih, w_hh, b_sum, h1, W1, const2);

    dim3 ggrid(512 / BN, (B_ + BM - 1) / BM);
    int  egrid = (B_ * D + 255) / 256;
    int  agrid = (B_ + WPB - 1) / WPB;

    // step 1: query = h1 (broadcast) -> out1
    attn_kernel<<<agrid, 192, 0, stream>>>(x, h1, 1, row_ptr, outbuf, nullptr, B_);
    // step 2: gates = const2 + out1 @ W2^T ; c_prev = c1 (broadcast)
    lstm_gemm_kernel<<<ggrid, 256, 0, stream>>>(outbuf, W2, 256, nullptr,
                                                nullptr, 0, const2, gates, B_);
    lstm_elem_kernel<<<egrid, 256, 0, stream>>>(gates, c1, 1, cbuf, hbuf, B_);
    attn_kernel<<<agrid, 192, 0, stream>>>(x, hbuf, 0, row_ptr, outbuf, nullptr, B_);
    // step 3: gates = b_sum + h2 @ W1^T + out2 @ W2^T
    lstm_gemm_kernel<<<ggrid, 256, 0, stream>>>(hbuf, W1, 128, outbuf, W2, 256,
                                                b_sum, gates, B_);
    lstm_elem_kernel<<<egrid, 256, 0, stream>>>(gates, cbuf, 0, cbuf, hbuf, B_);
    // step 3 attention writes final q_star = [h3, out3] directly to d_out
    attn_kernel<<<agrid, 192, 0, stream>>>(x, hbuf, 0, row_ptr, nullptr,
                                           (float*)d_out, B_);
}

// Round 3
// 641.075 us; speedup vs baseline: 2.4240x; 2.4240x over previous
//
#include <hip/hip_runtime.h>

#define D 128
#define EPS 1e-10f
#define TILE 32
#define WPB 3
#define NBLK 256

// ---------------------------------------------------------------------------
// async global -> LDS, 16B per lane (dest = base + lane*16, linear)
// ---------------------------------------------------------------------------
__device__ __forceinline__ void gload16(const float* g, float* l) {
    __builtin_amdgcn_global_load_lds(
        (const __attribute__((address_space(1))) void*)g,
        (__attribute__((address_space(3))) void*)l, 16, 0, 0);
}

// scalar load of row_ptr[idx], row_ptr[idx+1] (lgkmcnt path — keeps vmcnt
// counting clean for the gload_lds pipeline)
__device__ __forceinline__ unsigned long long sload2(const int* rp, int idx) {
    unsigned long long r;
    int off = __builtin_amdgcn_readfirstlane(idx << 2);
    asm volatile("s_load_dwordx2 %0, %1, %2\n\ts_waitcnt lgkmcnt(0)"
                 : "=s"(r) : "s"(rp), "s"(off) : "memory");
    return r;
}

__device__ __forceinline__ void wait_vm(int nn) {
    switch (nn) {
    case 0:  asm volatile("s_waitcnt vmcnt(0)" ::: "memory"); break;
    case 1:  asm volatile("s_waitcnt vmcnt(1)" ::: "memory"); break;
    case 2:  asm volatile("s_waitcnt vmcnt(2)" ::: "memory"); break;
    case 3:  asm volatile("s_waitcnt vmcnt(3)" ::: "memory"); break;
    case 16: asm volatile("s_waitcnt vmcnt(16)" ::: "memory"); break;
    case 17: asm volatile("s_waitcnt vmcnt(17)" ::: "memory"); break;
    case 18: asm volatile("s_waitcnt vmcnt(18)" ::: "memory"); break;
    default: asm volatile("s_waitcnt vmcnt(19)" ::: "memory"); break;
    }
}

// ---------------------------------------------------------------------------
// K1: row_ptr via binary search (node2graph sorted)
// ---------------------------------------------------------------------------
__global__ void rowptr_kernel(const int* __restrict__ n2g, int N_, int B_,
                              int* __restrict__ row_ptr) {
    int b = blockIdx.x * 256 + threadIdx.x;
    if (b > B_) return;
    if (b == B_) { row_ptr[b] = N_; return; }
    int lo = 0, hi = N_;
    while (lo < hi) {
        int mid = (lo + hi) >> 1;
        if (n2g[mid] < b) lo = mid + 1; else hi = mid;
    }
    row_ptr[b] = lo;
}

// ---------------------------------------------------------------------------
// K2: b_sum = b_ih + b_hh; step-1 constants h1, c1
// ---------------------------------------------------------------------------
__global__ void init_consts_kernel(const float* __restrict__ b_ih,
                                   const float* __restrict__ b_hh,
                                   float* __restrict__ b_sum,
                                   float* __restrict__ c1,
                                   float* __restrict__ h1) {
    int t = threadIdx.x;  // 512 threads, 1 block
    __shared__ float bs[512];
    float v = b_ih[t] + b_hh[t];
    b_sum[t] = v;
    bs[t] = v;
    __syncthreads();
    if (t < D) {
        float ig = 1.f / (1.f + __expf(-bs[t]));
        float gg = tanhf(bs[256 + t]);
        float c  = ig * gg;
        float og = 1.f / (1.f + __expf(-bs[384 + t]));
        c1[t] = c;
        h1[t] = og * tanhf(c);
    }
}

// ---------------------------------------------------------------------------
// K3: W1 = w_ih[:, :D] + w_hh; const2 = b_sum + W1 @ h1
// ---------------------------------------------------------------------------
__global__ void init_w1_kernel(const float* __restrict__ w_ih,
                               const float* __restrict__ w_hh,
                               const float* __restrict__ b_sum,
                               const float* __restrict__ h1,
                               float* __restrict__ W1,
                               float* __restrict__ const2) {
    int j = blockIdx.x, k = threadIdx.x;
    float w = w_ih[j * 256 + k] + w_hh[j * 128 + k];
    W1[j * 128 + k] = w;
    __shared__ float red[128];
    red[k] = w * h1[k];
    __syncthreads();
    for (int s = 64; s > 0; s >>= 1) {
        if (k < s) red[k] += red[k + s];
        __syncthreads();
    }
    if (k == 0) const2[j] = b_sum[j] + red[0];
}

// ---------------------------------------------------------------------------
// K4: tiled GEMM: gates[b][j] = base[j] + A1[b]·Wa[j] (+ A2[b]·Wb[j])
// ---------------------------------------------------------------------------
#define BM 64
#define BN 64
#define BK 32
__global__ __launch_bounds__(256) void lstm_gemm_kernel(
    const float* __restrict__ A1, const float* __restrict__ Wa, int wa_stride,
    const float* __restrict__ A2, const float* __restrict__ Wb, int wb_stride,
    const float* __restrict__ base, float* __restrict__ gates, int B_) {
    __shared__ float As[BM][BK + 1];
    __shared__ float Bs[BN][BK + 1];
    int b0 = blockIdx.y * BM;
    int j0 = blockIdx.x * BN;
    int tid = threadIdx.x;
    int tx = tid & 15, ty = tid >> 4;
    float acc[4][4] = {};
    int nphase = A2 ? 2 : 1;
    for (int phase = 0; phase < nphase; phase++) {
        const float* A = phase ? A2 : A1;
        const float* W = phase ? Wb : Wa;
        int ws = phase ? wb_stride : wa_stride;
        for (int k0 = 0; k0 < 128; k0 += BK) {
            __syncthreads();
            for (int i = tid; i < BM * BK; i += 256) {
                int r = i >> 5, cc = i & 31;
                int bb = b0 + r;
                As[r][cc] = (bb < B_) ? A[(size_t)bb * D + k0 + cc] : 0.f;
            }
            for (int i = tid; i < BN * BK; i += 256) {
                int r = i >> 5, cc = i & 31;
                Bs[r][cc] = W[(size_t)(j0 + r) * ws + k0 + cc];
            }
            __syncthreads();
#pragma unroll
            for (int kk = 0; kk < BK; kk++) {
                float av[4], bv[4];
#pragma unroll
                for (int i = 0; i < 4; i++) av[i] = As[ty * 4 + i][kk];
#pragma unroll
                for (int j = 0; j < 4; j++) bv[j] = Bs[tx * 4 + j][kk];
#pragma unroll
                for (int i = 0; i < 4; i++)
#pragma unroll
                    for (int j = 0; j < 4; j++) acc[i][j] += av[i] * bv[j];
            }
        }
    }
    for (int i = 0; i < 4; i++) {
        int bb = b0 + ty * 4 + i;
        if (bb >= B_) continue;
        for (int j = 0; j < 4; j++) {
            int jj = j0 + tx * 4 + j;
            gates[(size_t)bb * 512 + jj] = acc[i][j] + base[jj];
        }
    }
}

// ---------------------------------------------------------------------------
// K5: elementwise LSTM state update from gates
// ---------------------------------------------------------------------------
__global__ void lstm_elem_kernel(const float* __restrict__ gates,
                                 const float* __restrict__ c_prev, int c_bcast,
                                 float* __restrict__ c_out,
                                 float* __restrict__ h_out, int B_) {
    int t = blockIdx.x * 256 + threadIdx.x;
    if (t >= B_ * D) return;
    int b = t >> 7, d = t & (D - 1);
    const float* g = gates + (size_t)b * 512;
    float ig = 1.f / (1.f + __expf(-g[d]));
    float fg = 1.f / (1.f + __expf(-g[128 + d]));
    float gg = tanhf(g[256 + d]);
    float og = 1.f / (1.f + __expf(-g[384 + d]));
    float cp = c_bcast ? c_prev[d] : c_prev[t];
    float c = fg * cp + ig * gg;
    c_out[t] = c;
    h_out[t] = og * tanhf(c);
}

// ---------------------------------------------------------------------------
// K6: attention — wave-per-graph, persistent waves, global_load_lds double-
// buffered pipeline with counted vmcnt. No barriers, no reg staging (no
// spill). LDS rotation swizzle realized by pre-swizzling the global source
// (gload_lds dest is linear): content(row, s) = x[t0+row][ (s-row)&31 ].
// ---------------------------------------------------------------------------
__global__ __launch_bounds__(192, 1) void attn_kernel(
    const float* __restrict__ x, const float* __restrict__ q_src, int q_bcast,
    const int* __restrict__ row_ptr, float* __restrict__ out,
    float* __restrict__ final_out, int B_) {

    __shared__ float xs[WPB][2][TILE * D];  // 2 x 16 KB per wave
    __shared__ float qs[WPB][2][256];       // 2 x 1 KB per wave
    __shared__ float wsh[WPB][TILE];

    const int tid  = threadIdx.x;
    const int wave = tid >> 6;
    const int lane = tid & 63;
    const int NW   = gridDim.x * WPB;

    const int p   = lane >> 5;   // row parity (stage + accumulate)
    const int sc  = lane & 31;   // slot / dim-column id
    const int n   = lane >> 1;   // node id (dot)
    const int h   = lane & 1;
    const int h16 = h << 4;

    float* xb[2] = {xs[wave][0], xs[wave][1]};
    float* qb[2] = {qs[wave][0], qs[wave][1]};
    float* wsw   = wsh[wave];

    auto issue_tile = [&](int t0, int e_, float* dst) {
#pragma unroll
        for (int j = 0; j < 16; j++) {
            int row = 2 * j + p;                    // in-tile row
            int rg  = t0 + row;
            rg = (rg < e_) ? rg : (e_ - 1);         // clamp (values masked)
            int col = (sc - row) & 31;              // pre-swizzled source col
            gload16(x + ((size_t)rg * D + (col << 2)), dst + j * 256);
        }
    };
    auto issue_q = [&](int bq, float* dst) {
        const float* qp = q_bcast ? q_src : q_src + (size_t)bq * D;
        gload16(qp + (sc << 2), dst);               // lanes 32-63 duplicate
    };

    const int S = out ? 1 : 2;                      // stores per finalize
    int b = blockIdx.x * WPB + wave;
    if (b >= B_) return;

    unsigned long long se0 = sload2(row_ptr, b);
    int s = (int)(se0 & 0xffffffffull), e = (int)(se0 >> 32);
    int cur = 0, qc = 0, ps = 0;
    issue_q(b, qb[0]);
    if (s < e) issue_tile(s, e, xb[0]);

    while (1) {
        float m = -1e30f, lsum = 0.f;
        float ax = 0.f, ay = 0.f, az = 0.f, aw = 0.f;
        int sn = 0, en = 0;
        int bn = b + NW;
        int have_next = (bn < B_);

        if (s < e) {
            for (int t0 = s; t0 < e; t0 += TILE) {
                int nt = e - t0; nt = (nt < TILE) ? nt : TILE;
                int just;
                if (t0 + TILE < e) {
                    issue_tile(t0 + TILE, e, xb[cur ^ 1]);
                    just = 16;
                } else if (have_next) {
                    unsigned long long se2 = sload2(row_ptr, bn);
                    sn = (int)(se2 & 0xffffffffull); en = (int)(se2 >> 32);
                    issue_q(bn, qb[qc ^ 1]);
                    just = 1;
                    if (sn < en) { issue_tile(sn, en, xb[cur ^ 1]); just = 17; }
                } else {
                    just = 0;
                }
                wait_vm(just + ps); ps = 0;   // everything older is resident

                const float4* xw4 = (const float4*)xb[cur];
                const float4* qw4 = (const float4*)qb[qc];

                // dot: 2 lanes/node, 64 dims each, swizzled b128 reads
                float pd = 0.f;
#pragma unroll
                for (int j = 0; j < 16; j++) {
                    float4 xv = xw4[(n << 5) + ((h16 + j + n) & 31)];
                    float4 qv = qw4[h16 + j];
                    pd += xv.x * qv.x + xv.y * qv.y + xv.z * qv.z + xv.w * qv.w;
                }
                pd += __shfl_xor(pd, 1);
                float prod = (n < nt) ? pd : -1e30f;

                float tmax = prod;
#pragma unroll
                for (int mk = 2; mk <= 32; mk <<= 1)
                    tmax = fmaxf(tmax, __shfl_xor(tmax, mk));
                float m_new = fmaxf(m, tmax);
                float r = __expf(m - m_new);       // first tile: 0
                float w = __expf(prod - m_new);    // masked nodes: 0

                float tsum = w;
#pragma unroll
                for (int mk = 2; mk <= 32; mk <<= 1)
                    tsum += __shfl_xor(tsum, mk);
                lsum = lsum * r + tsum;

                if (h == 0) wsw[n] = w;            // zeros tail (w==0 masked)

                ax *= r; ay *= r; az *= r; aw *= r;
#pragma unroll
                for (int i = 0; i < 16; i++) {
                    int row = 2 * i + p;
                    float wt = wsw[row];
                    float4 xv = xw4[(row << 5) + ((sc + row) & 31)];
                    ax += wt * xv.x; ay += wt * xv.y;
                    az += wt * xv.z; aw += wt * xv.w;
                }
                m = m_new;
                cur ^= 1;
            }
        } else {
            // empty graph: still run the prefetch link of the pipeline
            int just = 0;
            if (have_next) {
                unsigned long long se2 = sload2(row_ptr, bn);
                sn = (int)(se2 & 0xffffffffull); en = (int)(se2 >> 32);
                issue_q(bn, qb[qc ^ 1]);
                just = 1;
                if (sn < en) { issue_tile(sn, en, xb[cur ^ 1]); just = 17; cur ^= 1; }
            }
            wait_vm(just + ps); ps = 0;
        }

        // finalize graph b (q(b) resident in qb[qc])
        ax += __shfl_xor(ax, 32);
        ay += __shfl_xor(ay, 32);
        az += __shfl_xor(az, 32);
        aw += __shfl_xor(aw, 32);
        float inv = 1.f / (lsum + EPS);
        float4 o = {ax * inv, ay * inv, az * inv, aw * inv};
        if (p == 0) {
            if (out) {
                ((float4*)out)[(size_t)b * 32 + sc] = o;
            } else {
                const float4* q4r = (const float4*)qb[qc];
                float4 qv = q4r[sc];
                float4* fo = (float4*)(final_out + (size_t)b * 256);
                fo[sc] = qv;
                fo[32 + sc] = o;
            }
        }
        ps = S;
        if (!have_next) break;
        b = bn; s = sn; e = en; qc ^= 1;
    }
}

// ---------------------------------------------------------------------------
extern "C" void kernel_launch(void* const* d_in, const int* in_sizes, int n_in,
                              void* d_out, int out_size, void* d_ws,
                              size_t ws_size, hipStream_t stream) {
    const float* x    = (const float*)d_in[0];
    const float* w_ih = (const float*)d_in[1];
    const float* w_hh = (const float*)d_in[2];
    const float* b_ih = (const float*)d_in[3];
    const float* b_hh = (const float*)d_in[4];
    const int*   n2g  = (const int*)d_in[5];

    int N_ = in_sizes[0] / D;     // 1,000,000
    int B_ = out_size / (2 * D);  // 10,000

    char* wsb = (char*)d_ws;
    size_t off = 0;
    auto carve = [&](size_t bytes) {
        void* pp = wsb + off;
        off = (off + bytes + 255) & ~(size_t)255;
        return pp;
    };
    int*   row_ptr = (int*)carve((size_t)(B_ + 1) * 4);
    float* b_sum   = (float*)carve(512 * 4);
    float* c1      = (float*)carve(D * 4);
    float* h1      = (float*)carve(D * 4);
    float* const2  = (float*)carve(512 * 4);
    float* W1      = (float*)carve((size_t)512 * D * 4);
    float* hbuf    = (float*)carve((size_t)B_ * D * 4);
    float* cbuf    = (float*)carve((size_t)B_ * D * 4);
    float* outbuf  = (float*)carve((size_t)B_ * D * 4);
    float* gates   = (float*)carve((size_t)B_ * 512 * 4);
    (void)ws_size;

    const float* W2 = w_ih + D;  // rows of w_ih, col offset 128, stride 256

    rowptr_kernel<<<(B_ + 1 + 255) / 256, 256, 0, stream>>>(n2g, N_, B_, row_ptr);
    init_consts_kernel<<<1, 512, 0, stream>>>(b_ih, b_hh, b_sum, c1, h1);
    init_w1_kernel<<<512, 128, 0, stream>>>(w_ih, w_hh, b_sum, h1, W1, const2);

    dim3 ggrid(512 / BN, (B_ + BM - 1) / BM);
    int  egrid = (B_ * D + 255) / 256;

    // step 1: query = h1 (broadcast) -> out1
    attn_kernel<<<NBLK, 192, 0, stream>>>(x, h1, 1, row_ptr, outbuf, nullptr, B_);
    // step 2: gates = const2 + out1 @ W2^T ; c_prev = c1 (broadcast)
    lstm_gemm_kernel<<<ggrid, 256, 0, stream>>>(outbuf, W2, 256, nullptr,
                                                nullptr, 0, const2, gates, B_);
    lstm_elem_kernel<<<egrid, 256, 0, stream>>>(gates, c1, 1, cbuf, hbuf, B_);
    attn_kernel<<<NBLK, 192, 0, stream>>>(x, hbuf, 0, row_ptr, outbuf, nullptr, B_);
    // step 3: gates = b_sum + h2 @ W1^T + out2 @ W2^T
    lstm_gemm_kernel<<<ggrid, 256, 0, stream>>>(hbuf, W1, 128, outbuf, W2, 256,
                                                b_sum, gates, B_);
    lstm_elem_kernel<<<egrid, 256, 0, stream>>>(gates, cbuf, 0, cbuf, hbuf, B_);
    // step 3 attention writes final q_star = [h3, out3] directly to d_out
    attn_kernel<<<NBLK, 192, 0, stream>>>(x, hbuf, 0, row_ptr, nullptr,
                                          (float*)d_out, B_);
}

// Round 4
// 586.027 us; speedup vs baseline: 2.6517x; 1.0939x over previous
//
#include <hip/hip_runtime.h>

#define D 128
#define EPS 1e-10f
#define TILE 16
#define WPB 4
#define NBLK 512
#define THR 14.0f

// ---------------------------------------------------------------------------
// async global -> LDS, 16B per lane (dest = base + lane*16, linear)
// ---------------------------------------------------------------------------
__device__ __forceinline__ void gload16(const float* g, float* l) {
    __builtin_amdgcn_global_load_lds(
        (const __attribute__((address_space(1))) void*)g,
        (__attribute__((address_space(3))) void*)l, 16, 0, 0);
}

// scalar load of row_ptr[idx], row_ptr[idx+1] (lgkmcnt path — keeps vmcnt
// counting clean for the gload_lds pipeline)
__device__ __forceinline__ unsigned long long sload2(const int* rp, int idx) {
    unsigned long long r;
    int off = __builtin_amdgcn_readfirstlane(idx << 2);
    asm volatile("s_load_dwordx2 %0, %1, %2\n\ts_waitcnt lgkmcnt(0)"
                 : "=s"(r) : "s"(rp), "s"(off) : "memory");
    return r;
}

__device__ __forceinline__ void wait_vm(int nn) {
    switch (nn) {
    case 0:  asm volatile("s_waitcnt vmcnt(0)" ::: "memory"); break;
    case 1:  asm volatile("s_waitcnt vmcnt(1)" ::: "memory"); break;
    case 2:  asm volatile("s_waitcnt vmcnt(2)" ::: "memory"); break;
    case 3:  asm volatile("s_waitcnt vmcnt(3)" ::: "memory"); break;
    case 8:  asm volatile("s_waitcnt vmcnt(8)" ::: "memory"); break;
    case 9:  asm volatile("s_waitcnt vmcnt(9)" ::: "memory"); break;
    case 10: asm volatile("s_waitcnt vmcnt(10)" ::: "memory"); break;
    case 11: asm volatile("s_waitcnt vmcnt(11)" ::: "memory"); break;
    default: asm volatile("s_waitcnt vmcnt(0)" ::: "memory"); break;
    }
}

// bit-mixed dim-group -> slot permutation (keeps every LDS phase <=2-way):
// delta(d) = (d&24) | ((d + 2*(d>>3)) & 7);  inverse: q=u>>3, low=(u-2q)&7
__device__ __forceinline__ int dperm(int d) {
    return (d & 24) | ((d + 2 * (d >> 3)) & 7);
}
__device__ __forceinline__ int dperm_inv(int u) {
    int q = u >> 3;
    return (q << 3) | ((u - 2 * q) & 7);
}

// ---------------------------------------------------------------------------
// K1: row_ptr via binary search (node2graph sorted)
// ---------------------------------------------------------------------------
__global__ void rowptr_kernel(const int* __restrict__ n2g, int N_, int B_,
                              int* __restrict__ row_ptr) {
    int b = blockIdx.x * 256 + threadIdx.x;
    if (b > B_) return;
    if (b == B_) { row_ptr[b] = N_; return; }
    int lo = 0, hi = N_;
    while (lo < hi) {
        int mid = (lo + hi) >> 1;
        if (n2g[mid] < b) lo = mid + 1; else hi = mid;
    }
    row_ptr[b] = lo;
}

// ---------------------------------------------------------------------------
// K2: b_sum = b_ih + b_hh; step-1 constants h1, c1
// ---------------------------------------------------------------------------
__global__ void init_consts_kernel(const float* __restrict__ b_ih,
                                   const float* __restrict__ b_hh,
                                   float* __restrict__ b_sum,
                                   float* __restrict__ c1,
                                   float* __restrict__ h1) {
    int t = threadIdx.x;  // 512 threads, 1 block
    __shared__ float bs[512];
    float v = b_ih[t] + b_hh[t];
    b_sum[t] = v;
    bs[t] = v;
    __syncthreads();
    if (t < D) {
        float ig = 1.f / (1.f + __expf(-bs[t]));
        float gg = tanhf(bs[256 + t]);
        float c  = ig * gg;
        float og = 1.f / (1.f + __expf(-bs[384 + t]));
        c1[t] = c;
        h1[t] = og * tanhf(c);
    }
}

// ---------------------------------------------------------------------------
// K3: W1 = w_ih[:, :D] + w_hh; const2 = b_sum + W1 @ h1
// ---------------------------------------------------------------------------
__global__ void init_w1_kernel(const float* __restrict__ w_ih,
                               const float* __restrict__ w_hh,
                               const float* __restrict__ b_sum,
                               const float* __restrict__ h1,
                               float* __restrict__ W1,
                               float* __restrict__ const2) {
    int j = blockIdx.x, k = threadIdx.x;
    float w = w_ih[j * 256 + k] + w_hh[j * 128 + k];
    W1[j * 128 + k] = w;
    __shared__ float red[128];
    red[k] = w * h1[k];
    __syncthreads();
    for (int s = 64; s > 0; s >>= 1) {
        if (k < s) red[k] += red[k + s];
        __syncthreads();
    }
    if (k == 0) const2[j] = b_sum[j] + red[0];
}

// ---------------------------------------------------------------------------
// K4: tiled GEMM: gates[b][j] = base[j] + A1[b]·Wa[j] (+ A2[b]·Wb[j])
// ---------------------------------------------------------------------------
#define BM 64
#define BN 64
#define BK 32
__global__ __launch_bounds__(256) void lstm_gemm_kernel(
    const float* __restrict__ A1, const float* __restrict__ Wa, int wa_stride,
    const float* __restrict__ A2, const float* __restrict__ Wb, int wb_stride,
    const float* __restrict__ base, float* __restrict__ gates, int B_) {
    __shared__ float As[BM][BK + 1];
    __shared__ float Bs[BN][BK + 1];
    int b0 = blockIdx.y * BM;
    int j0 = blockIdx.x * BN;
    int tid = threadIdx.x;
    int tx = tid & 15, ty = tid >> 4;
    float acc[4][4] = {};
    int nphase = A2 ? 2 : 1;
    for (int phase = 0; phase < nphase; phase++) {
        const float* A = phase ? A2 : A1;
        const float* W = phase ? Wb : Wa;
        int ws = phase ? wb_stride : wa_stride;
        for (int k0 = 0; k0 < 128; k0 += BK) {
            __syncthreads();
            for (int i = tid; i < BM * BK; i += 256) {
                int r = i >> 5, cc = i & 31;
                int bb = b0 + r;
                As[r][cc] = (bb < B_) ? A[(size_t)bb * D + k0 + cc] : 0.f;
            }
            for (int i = tid; i < BN * BK; i += 256) {
                int r = i >> 5, cc = i & 31;
                Bs[r][cc] = W[(size_t)(j0 + r) * ws + k0 + cc];
            }
            __syncthreads();
#pragma unroll
            for (int kk = 0; kk < BK; kk++) {
                float av[4], bv[4];
#pragma unroll
                for (int i = 0; i < 4; i++) av[i] = As[ty * 4 + i][kk];
#pragma unroll
                for (int j = 0; j < 4; j++) bv[j] = Bs[tx * 4 + j][kk];
#pragma unroll
                for (int i = 0; i < 4; i++)
#pragma unroll
                    for (int j = 0; j < 4; j++) acc[i][j] += av[i] * bv[j];
            }
        }
    }
    for (int i = 0; i < 4; i++) {
        int bb = b0 + ty * 4 + i;
        if (bb >= B_) continue;
        for (int j = 0; j < 4; j++) {
            int jj = j0 + tx * 4 + j;
            gates[(size_t)bb * 512 + jj] = acc[i][j] + base[jj];
        }
    }
}

// ---------------------------------------------------------------------------
// K5: elementwise LSTM state update from gates
// ---------------------------------------------------------------------------
__global__ void lstm_elem_kernel(const float* __restrict__ gates,
                                 const float* __restrict__ c_prev, int c_bcast,
                                 float* __restrict__ c_out,
                                 float* __restrict__ h_out, int B_) {
    int t = blockIdx.x * 256 + threadIdx.x;
    if (t >= B_ * D) return;
    int b = t >> 7, d = t & (D - 1);
    const float* g = gates + (size_t)b * 512;
    float ig = 1.f / (1.f + __expf(-g[d]));
    float fg = 1.f / (1.f + __expf(-g[128 + d]));
    float gg = tanhf(g[256 + d]);
    float og = 1.f / (1.f + __expf(-g[384 + d]));
    float cp = c_bcast ? c_prev[d] : c_prev[t];
    float c = fg * cp + ig * gg;
    c_out[t] = c;
    h_out[t] = og * tanhf(c);
}

// ---------------------------------------------------------------------------
// K6: attention — wave-per-graph, persistent, gload_lds double-buffer with
// counted vmcnt. TILE=16 (8 loads/tile), 4 waves/block, 2 blocks/CU ->
// 2 waves/SIMD. Defer-max softmax (THR). Bit-mixed LDS permutation dperm
// applied via pre-swizzled GLOBAL source (LDS dest linear): slot layout
// content(row, s) = x[row][ dperm_inv((s - row)&31) ] (float4 granularity).
// All LDS read phases (dot 4-lanes/node, acc, q) are <=2-way per quarter.
// ---------------------------------------------------------------------------
__global__ __launch_bounds__(256, 2) void attn_kernel(
    const float* __restrict__ x, const float* __restrict__ q_src, int q_bcast,
    const int* __restrict__ row_ptr, float* __restrict__ out,
    float* __restrict__ final_out, int B_) {

    __shared__ float xs[WPB][2][TILE * D];  // 2 x 8 KB per wave
    __shared__ float qs[WPB][2][256];       // 2 x 1 KB per wave
    __shared__ float wsh[WPB][TILE];

    const int tid  = threadIdx.x;
    const int wave = tid >> 6;
    const int lane = tid & 63;
    const int NW   = gridDim.x * WPB;

    const int p    = lane >> 5;        // staging/acc parity
    const int sc   = lane & 31;        // slot / dim-group id
    const int n    = lane >> 2;        // node id (dot): 0..15
    const int qd   = lane & 3;         // dim quarter (dot)
    const int qdb  = qd << 3;          // dperm(8qd+j) = qdb | ((j+2qd)&7)
    const int qd2  = qd << 1;
    const int dacc = dperm(sc);        // acc slot base
    const int qsrc = dperm_inv(sc);    // q staging source col

    float* xb[2] = {xs[wave][0], xs[wave][1]};
    float* qb[2] = {qs[wave][0], qs[wave][1]};
    float* wsw   = wsh[wave];

    auto issue_tile = [&](int t0, int e_, float* dst) {
#pragma unroll
        for (int j = 0; j < 8; j++) {
            int row = 2 * j + p;                    // in-tile row
            int rg  = t0 + row;
            rg = (rg < e_) ? rg : (e_ - 1);         // clamp (masked by w=0)
            int u = (sc - row) & 31;
            int col = dperm_inv(u);                 // pre-swizzled source col
            gload16(x + ((size_t)rg * D + (col << 2)), dst + j * 256);
        }
    };
    auto issue_q = [&](int bq, float* dst) {
        const float* qp = q_bcast ? q_src : q_src + (size_t)bq * D;
        gload16(qp + (qsrc << 2), dst);             // lanes 32-63 duplicate
    };

    const int S = out ? 1 : 2;                      // stores per finalize
    int b = blockIdx.x * WPB + wave;
    if (b >= B_) return;

    unsigned long long se0 = sload2(row_ptr, b);
    int s = (int)(se0 & 0xffffffffull), e = (int)(se0 >> 32);
    int cur = 0, qc = 0, ps = 0;
    issue_q(b, qb[0]);
    if (s < e) issue_tile(s, e, xb[0]);

    while (1) {
        float m = -1e30f, lsum = 0.f;
        float ax = 0.f, ay = 0.f, az = 0.f, aw = 0.f;
        int sn = 0, en = 0;
        int bn = b + NW;
        int have_next = (bn < B_);

        if (s < e) {
            for (int t0 = s; t0 < e; t0 += TILE) {
                int nt = e - t0; nt = (nt < TILE) ? nt : TILE;
                int just;
                if (t0 + TILE < e) {
                    issue_tile(t0 + TILE, e, xb[cur ^ 1]);
                    just = 8;
                } else if (have_next) {
                    unsigned long long se2 = sload2(row_ptr, bn);
                    sn = (int)(se2 & 0xffffffffull); en = (int)(se2 >> 32);
                    issue_q(bn, qb[qc ^ 1]);
                    just = 1;
                    if (sn < en) { issue_tile(sn, en, xb[cur ^ 1]); just = 9; }
                } else {
                    just = 0;
                }
                wait_vm(just + ps); ps = 0;

                const float4* xw4 = (const float4*)xb[cur];
                const float4* qw4 = (const float4*)qb[qc];

                // dot: 4 lanes/node, 32 dims each; 2 accumulators
                float pd0 = 0.f, pd1 = 0.f;
#pragma unroll
                for (int j = 0; j < 8; j += 2) {
                    int sl0 = ((qdb | ((j + qd2) & 7)) + n) & 31;
                    int sl1 = ((qdb | ((j + 1 + qd2) & 7)) + n) & 31;
                    float4 xv0 = xw4[(n << 5) + sl0];
                    float4 qv0 = qw4[qdb | ((j + qd2) & 7)];
                    float4 xv1 = xw4[(n << 5) + sl1];
                    float4 qv1 = qw4[qdb | ((j + 1 + qd2) & 7)];
                    pd0 += xv0.x * qv0.x + xv0.y * qv0.y + xv0.z * qv0.z + xv0.w * qv0.w;
                    pd1 += xv1.x * qv1.x + xv1.y * qv1.y + xv1.z * qv1.z + xv1.w * qv1.w;
                }
                float pd = pd0 + pd1;
                pd += __shfl_xor(pd, 1);
                pd += __shfl_xor(pd, 2);
                float prod = (n < nt) ? pd : -1e30f;

                // defer-max: fast path skips the max tree + rescale entirely
                if (!__all(prod <= m + THR)) {
                    float tmax = prod;
#pragma unroll
                    for (int mk = 4; mk <= 32; mk <<= 1)
                        tmax = fmaxf(tmax, __shfl_xor(tmax, mk));
                    float m_new = fmaxf(m, tmax);
                    float r = __expf(m - m_new);   // first tile: 0
                    lsum *= r;
                    ax *= r; ay *= r; az *= r; aw *= r;
                    m = m_new;
                }
                float w = __expf(prod - m);        // masked nodes: 0

                float tsum = w;
#pragma unroll
                for (int mk = 4; mk <= 32; mk <<= 1)
                    tsum += __shfl_xor(tsum, mk);
                lsum += tsum;

                if (qd == 0) wsw[n] = w;           // tail rows get w=0

                // accumulate: lane owns dim-group sc, rows of parity p
#pragma unroll
                for (int i = 0; i < 8; i++) {
                    int row = 2 * i + p;
                    float wt = wsw[row];
                    float4 xv = xw4[(row << 5) + ((dacc + row) & 31)];
                    ax += wt * xv.x; ay += wt * xv.y;
                    az += wt * xv.z; aw += wt * xv.w;
                }
                cur ^= 1;
            }
        } else {
            // empty graph: still run the prefetch link of the pipeline
            int just = 0;
            if (have_next) {
                unsigned long long se2 = sload2(row_ptr, bn);
                sn = (int)(se2 & 0xffffffffull); en = (int)(se2 >> 32);
                issue_q(bn, qb[qc ^ 1]);
                just = 1;
                if (sn < en) { issue_tile(sn, en, xb[cur ^ 1]); just = 9; cur ^= 1; }
            }
            wait_vm(just + ps); ps = 0;
        }

        // finalize graph b (q(b) resident in qb[qc])
        ax += __shfl_xor(ax, 32);
        ay += __shfl_xor(ay, 32);
        az += __shfl_xor(az, 32);
        aw += __shfl_xor(aw, 32);
        float inv = 1.f / (lsum + EPS);
        float4 o = {ax * inv, ay * inv, az * inv, aw * inv};
        if (p == 0) {
            if (out) {
                ((float4*)out)[(size_t)b * 32 + sc] = o;
            } else {
                const float4* q4r = (const float4*)qb[qc];
                float4 qv = q4r[dperm(sc)];        // un-permute q
                float4* fo = (float4*)(final_out + (size_t)b * 256);
                fo[sc] = qv;
                fo[32 + sc] = o;
            }
        }
        ps = S;
        if (!have_next) break;
        b = bn; s = sn; e = en; qc ^= 1;
    }
}

// ---------------------------------------------------------------------------
extern "C" void kernel_launch(void* const* d_in, const int* in_sizes, int n_in,
                              void* d_out, int out_size, void* d_ws,
                              size_t ws_size, hipStream_t stream) {
    const float* x    = (const float*)d_in[0];
    const float* w_ih = (const float*)d_in[1];
    const float* w_hh = (const float*)d_in[2];
    const float* b_ih = (const float*)d_in[3];
    const float* b_hh = (const float*)d_in[4];
    const int*   n2g  = (const int*)d_in[5];

    int N_ = in_sizes[0] / D;     // 1,000,000
    int B_ = out_size / (2 * D);  // 10,000

    char* wsb = (char*)d_ws;
    size_t off = 0;
    auto carve = [&](size_t bytes) {
        void* pp = wsb + off;
        off = (off + bytes + 255) & ~(size_t)255;
        return pp;
    };
    int*   row_ptr = (int*)carve((size_t)(B_ + 1) * 4);
    float* b_sum   = (float*)carve(512 * 4);
    float* c1      = (float*)carve(D * 4);
    float* h1      = (float*)carve(D * 4);
    float* const2  = (float*)carve(512 * 4);
    float* W1      = (float*)carve((size_t)512 * D * 4);
    float* hbuf    = (float*)carve((size_t)B_ * D * 4);
    float* cbuf    = (float*)carve((size_t)B_ * D * 4);
    float* outbuf  = (float*)carve((size_t)B_ * D * 4);
    float* gates   = (float*)carve((size_t)B_ * 512 * 4);
    (void)ws_size;

    const float* W2 = w_ih + D;  // rows of w_ih, col offset 128, stride 256

    rowptr_kernel<<<(B_ + 1 + 255) / 256, 256, 0, stream>>>(n2g, N_, B_, row_ptr);
    init_consts_kernel<<<1, 512, 0, stream>>>(b_ih, b_hh, b_sum, c1, h1);
    init_w1_kernel<<<512, 128, 0, stream>>>(w_ih, w_hh, b_sum, h1, W1, const2);

    dim3 ggrid(512 / BN, (B_ + BM - 1) / BM);
    int  egrid = (B_ * D + 255) / 256;

    // step 1: query = h1 (broadcast) -> out1
    attn_kernel<<<NBLK, 256, 0, stream>>>(x, h1, 1, row_ptr, outbuf, nullptr, B_);
    // step 2: gates = const2 + out1 @ W2^T ; c_prev = c1 (broadcast)
    lstm_gemm_kernel<<<ggrid, 256, 0, stream>>>(outbuf, W2, 256, nullptr,
                                                nullptr, 0, const2, gates, B_);
    lstm_elem_kernel<<<egrid, 256, 0, stream>>>(gates, c1, 1, cbuf, hbuf, B_);
    attn_kernel<<<NBLK, 256, 0, stream>>>(x, hbuf, 0, row_ptr, outbuf, nullptr, B_);
    // step 3: gates = b_sum + h2 @ W1^T + out2 @ W2^T
    lstm_gemm_kernel<<<ggrid, 256, 0, stream>>>(hbuf, W1, 128, outbuf, W2, 256,
                                                b_sum, gates, B_);
    lstm_elem_kernel<<<egrid, 256, 0, stream>>>(gates, cbuf, 0, cbuf, hbuf, B_);
    // step 3 attention writes final q_star = [h3, out3] directly to d_out
    attn_kernel<<<NBLK, 256, 0, stream>>>(x, hbuf, 0, row_ptr, nullptr,
                                          (float*)d_out, B_);
}